// Round 1
// baseline (682.577 us; speedup 1.0000x reference)
//
#include <hip/hip_runtime.h>
#include <math.h>

#define N_ROWS 16384
#define DMODEL 1024
#define DFF    4096

typedef _Float16 f16;
typedef __attribute__((ext_vector_type(4))) _Float16 f16x4;
typedef __attribute__((ext_vector_type(8))) _Float16 f16x8;
typedef __attribute__((ext_vector_type(4))) float f32x4;

__device__ inline void async_ld16(const f16* g, f16* l) {
  __builtin_amdgcn_global_load_lds(
      (__attribute__((address_space(1))) void*)(g),
      (__attribute__((address_space(3))) void*)(l),
      16, 0, 0);
}

// tanh via hw v_exp_f32: ~5 VALU ops vs libm tanhf's branchy ~40.
__device__ inline float fast_tanh(float x) {
  float t = __expf(2.0f * x);
  return 1.0f - 2.0f / (t + 1.0f);
}

__global__ void cast_to_f16(const float* __restrict__ src, f16* __restrict__ dst, int n) {
  int i = (blockIdx.x * blockDim.x + threadIdx.x) * 8;
  if (i >= n) return;
  float4 v0 = ((const float4*)(src + i))[0];
  float4 v1 = ((const float4*)(src + i))[1];
  f16x8 h = { (f16)v0.x, (f16)v0.y, (f16)v0.z, (f16)v0.w,
              (f16)v1.x, (f16)v1.y, (f16)v1.z, (f16)v1.w };
  *(f16x8*)(dst + i) = h;
}

#define BARRIER() asm volatile("s_barrier" ::: "memory")

// ---------------------------------------------------------------------------
// C[M,Nc] = tanh(A[M,K] @ B[Nc,K]^T + bias), f16 in/out, fp32 acc.
// 256x256 tile, BK=64, 512 thr (8 waves 2x4, per-wave 128x64 out).
// LDS 128KB: 2 bufs x (A 32KB + B 32KB), rows of 64 f16 = 128B.
// Schedule (per K-tile, 4 phases):
//   P0: ds_read k-half0 frags (12x b128) | bar | 16 MFMA (k0, m0-3) | bar
//   P1: ds_read k-half1 frags            | bar | 16 MFMA (k0, m4-7) |
//       lgkmcnt(0) | bar   <- all reads of buf[t&1] done chip-wide -> free
//   P2: stage 4/8 loads of tile t+2 -> buf[t&1] | bar | 16 MFMA (k1,m0-3)| bar
//   P3: stage 4/8 loads | 16 MFMA (k1, m4-7) | vmcnt(8) | bar
// vmcnt(8): the 8 loads issued this tile (t+2's) stay in flight across the
// boundary; everything older (tile t+1's 8) has retired -> t+1 readable.
// T2 swizzle: read byte ^= ((row&7)<<4); global source slot pre-XORed with
// the same involution, LDS dest linear (global_load_lds requirement, G#21).
// ---------------------------------------------------------------------------
template <int K>
__global__ __launch_bounds__(512, 2)
void gemm256_tanh(const f16* __restrict__ A, const f16* __restrict__ B,
                  const float* __restrict__ bias, f16* __restrict__ C, int Nc) {
  extern __shared__ __align__(16) char smem[];
  f16* lds = (f16*)smem;

  const int tid  = threadIdx.x;
  const int lane = tid & 63;
  const int wave = tid >> 6;
  const int wm = (wave >> 2) * 128;   // 2 wave-rows
  const int wn = (wave & 3) * 64;     // 4 wave-cols
  const int fr = lane & 15;
  const int g  = lane >> 4;
  // row&7 == fr&7 for every fragment row (wm, m*16 are multiples of 8)
  const int kxor = (fr & 7) << 4;
  const int cb0 = (g * 16) ^ kxor;       // byte col, k-half 0
  const int cb1 = (64 + g * 16) ^ kxor;  // byte col, k-half 1

  // T1: XCD-aware swizzle (nwg % 8 == 0 for both GEMMs here)
  const int nbx = gridDim.x;
  const int nwg = nbx * gridDim.y;
  const int lin = blockIdx.y * nbx + blockIdx.x;
  const int swz = (lin & 7) * (nwg >> 3) + (lin >> 3);
  const size_t row0 = (size_t)(swz % nbx) * 256;
  const size_t col0 = (size_t)(swz / nbx) * 256;

  // Staging: per operand per tile = 2048 16B chunks; thread owns chunks
  // c = q*512+tid (q=0..3). LDS dest linear: base + c*16B (wave-uniform base
  // + lane*16). Source slot pre-swizzled: slot ^ (row&7), both constant/thread.
  const int srow  = tid >> 3;                 // + q*64 = tile row
  const int sslot = (tid & 7) ^ (srow & 7);
  const f16* Ag[4]; const f16* Bg[4];
  int ldA[4], ldB[4];
#pragma unroll
  for (int q = 0; q < 4; ++q) {
    const int row = q * 64 + srow;
    Ag[q] = A + (row0 + row) * (size_t)K + sslot * 8;
    Bg[q] = B + (col0 + row) * (size_t)K + sslot * 8;
    const int c = q * 512 + tid;
    ldA[q] = c * 8;           // f16 offset in A region
    ldB[q] = 16384 + c * 8;   // f16 offset in B region
  }

  f32x4 acc[8][4] = {};
  constexpr int NT = K / 64;

  // prologue: stage tiles 0 and 1 (8 loads each, in order)
#pragma unroll
  for (int q = 0; q < 4; ++q) {
    async_ld16(Ag[q], lds + ldA[q]);
    async_ld16(Bg[q], lds + ldB[q]);
  }
#pragma unroll
  for (int q = 0; q < 4; ++q) {
    async_ld16(Ag[q] + 64, lds + 32768 + ldA[q]);
    async_ld16(Bg[q] + 64, lds + 32768 + ldB[q]);
  }
  asm volatile("s_waitcnt vmcnt(8)" ::: "memory");  // tile0 landed, tile1 in flight
  BARRIER();

#pragma unroll 2
  for (int t = 0; t < NT; ++t) {
    const char* Ts = smem + (t & 1) * 65536;        // A tile (bytes)
    const char* Us = Ts + 32768;                    // B tile
    f16* sd = lds + (t & 1) * 32768;                // stage dest (tile t+2)
    const int kpre = (t + 2) * 64;
    const bool pre = (t + 2) < NT;

    f16x8 a0[8], a1[8], b0[4], b1[4];
    // ---- P0 ----
#pragma unroll
    for (int m = 0; m < 8; ++m)
      a0[m] = *(const f16x8*)(Ts + (wm + m * 16 + fr) * 128 + cb0);
#pragma unroll
    for (int n = 0; n < 4; ++n)
      b0[n] = *(const f16x8*)(Us + (wn + n * 16 + fr) * 128 + cb0);
    BARRIER();
    __builtin_amdgcn_s_setprio(1);
#pragma unroll
    for (int m = 0; m < 4; ++m)
#pragma unroll
      for (int n = 0; n < 4; ++n)
        acc[m][n] = __builtin_amdgcn_mfma_f32_16x16x32_f16(a0[m], b0[n], acc[m][n], 0, 0, 0);
    __builtin_amdgcn_s_setprio(0);
    BARRIER();
    // ---- P1 ----
#pragma unroll
    for (int m = 0; m < 8; ++m)
      a1[m] = *(const f16x8*)(Ts + (wm + m * 16 + fr) * 128 + cb1);
#pragma unroll
    for (int n = 0; n < 4; ++n)
      b1[n] = *(const f16x8*)(Us + (wn + n * 16 + fr) * 128 + cb1);
    BARRIER();
    __builtin_amdgcn_s_setprio(1);
#pragma unroll
    for (int m = 4; m < 8; ++m)
#pragma unroll
      for (int n = 0; n < 4; ++n)
        acc[m][n] = __builtin_amdgcn_mfma_f32_16x16x32_f16(a0[m], b0[n], acc[m][n], 0, 0, 0);
    __builtin_amdgcn_s_setprio(0);
    asm volatile("s_waitcnt lgkmcnt(0)" ::: "memory");
    BARRIER();  // every wave's reads of buf[t&1] returned -> buffer free
    // ---- P2 ----
    if (pre) {
      async_ld16(Ag[0] + kpre, sd + ldA[0]);
      async_ld16(Bg[0] + kpre, sd + ldB[0]);
      async_ld16(Ag[1] + kpre, sd + ldA[1]);
      async_ld16(Bg[1] + kpre, sd + ldB[1]);
    }
    BARRIER();
    __builtin_amdgcn_s_setprio(1);
#pragma unroll
    for (int m = 0; m < 4; ++m)
#pragma unroll
      for (int n = 0; n < 4; ++n)
        acc[m][n] = __builtin_amdgcn_mfma_f32_16x16x32_f16(a1[m], b1[n], acc[m][n], 0, 0, 0);
    __builtin_amdgcn_s_setprio(0);
    BARRIER();
    // ---- P3 ----
    if (pre) {
      async_ld16(Ag[2] + kpre, sd + ldA[2]);
      async_ld16(Bg[2] + kpre, sd + ldB[2]);
      async_ld16(Ag[3] + kpre, sd + ldA[3]);
      async_ld16(Bg[3] + kpre, sd + ldB[3]);
    }
    __builtin_amdgcn_s_setprio(1);
#pragma unroll
    for (int m = 4; m < 8; ++m)
#pragma unroll
      for (int n = 0; n < 4; ++n)
        acc[m][n] = __builtin_amdgcn_mfma_f32_16x16x32_f16(a1[m], b1[n], acc[m][n], 0, 0, 0);
    __builtin_amdgcn_s_setprio(0);
    if (pre) asm volatile("s_waitcnt vmcnt(8)" ::: "memory");
    else     asm volatile("s_waitcnt vmcnt(0)" ::: "memory");  // tail: drain
    BARRIER();
  }

  // epilogue; C/D map: col=lane&15, row=(lane>>4)*4+reg [m89-verified]
#pragma unroll
  for (int m = 0; m < 8; ++m) {
#pragma unroll
    for (int n = 0; n < 4; ++n) {
      const size_t gcol = col0 + wn + n * 16 + fr;
      const float bia = bias[gcol];
      f16* Cp = C + (row0 + wm + m * 16 + g * 4) * (size_t)Nc + gcol;
#pragma unroll
      for (int r = 0; r < 4; ++r)
        Cp[(size_t)r * Nc] = (f16)fast_tanh(acc[m][n][r] + bia);
    }
  }
}

// out[row] = sigmoid(sum_k wx[row][k] * batch[row][k]); 256 thr/row, fp32 acc
__global__ void rowdot_sigmoid(const f16* __restrict__ wx, const float* __restrict__ batch,
                               float* __restrict__ out) {
  const int row = blockIdx.x;
  const int t = threadIdx.x;
  const f16* wr = wx + (size_t)row * DMODEL + t * 4;
  const float* br = batch + (size_t)row * DMODEL + t * 4;
  f16x4 h = *(const f16x4*)wr;
  float4 b4 = *(const float4*)br;
  float s = (float)h[0] * b4.x + (float)h[1] * b4.y + (float)h[2] * b4.z + (float)h[3] * b4.w;
#pragma unroll
  for (int off = 32; off > 0; off >>= 1) s += __shfl_down(s, off, 64);
  __shared__ float partial[4];
  if ((t & 63) == 0) partial[t >> 6] = s;
  __syncthreads();
  if (t == 0) {
    float tot = partial[0] + partial[1] + partial[2] + partial[3];
    out[row] = 1.0f / (1.0f + __expf(-tot));
  }
}

extern "C" void kernel_launch(void* const* d_in, const int* in_sizes, int n_in,
                              void* d_out, int out_size, void* d_ws, size_t ws_size,
                              hipStream_t stream) {
  const float* batch = (const float*)d_in[0];
  const float* W1    = (const float*)d_in[1];
  const float* b1    = (const float*)d_in[2];
  const float* W2    = (const float*)d_in[3];
  const float* b2    = (const float*)d_in[4];
  float* out = (float*)d_out;

  char* ws = (char*)d_ws;
  f16* batch_h = (f16*)ws;  ws += (size_t)N_ROWS * DMODEL * sizeof(f16);  //  32 MB
  f16* W1_h    = (f16*)ws;  ws += (size_t)DFF * DMODEL * sizeof(f16);     //   8 MB
  f16* W2_h    = (f16*)ws;  ws += (size_t)DMODEL * DFF * sizeof(f16);     //   8 MB
  f16* inner_h = (f16*)ws;  ws += (size_t)N_ROWS * DFF * sizeof(f16);     // 128 MB
  f16* wx_h    = (f16*)ws;  ws += (size_t)N_ROWS * DMODEL * sizeof(f16);  //  32 MB

  static bool attr_set = false;
  if (!attr_set) {
    (void)hipFuncSetAttribute((const void*)gemm256_tanh<DMODEL>,
                              hipFuncAttributeMaxDynamicSharedMemorySize, 131072);
    (void)hipFuncSetAttribute((const void*)gemm256_tanh<DFF>,
                              hipFuncAttributeMaxDynamicSharedMemorySize, 131072);
    attr_set = true;
  }

  const int nb = N_ROWS * DMODEL;
  const int nw = DFF * DMODEL;
  cast_to_f16<<<nb / 2048, 256, 0, stream>>>(batch, batch_h, nb);
  cast_to_f16<<<nw / 2048, 256, 0, stream>>>(W1, W1_h, nw);
  cast_to_f16<<<nw / 2048, 256, 0, stream>>>(W2, W2_h, nw);

  dim3 g1(N_ROWS / 256, DFF / 256);     // (64, 16)
  gemm256_tanh<DMODEL><<<g1, 512, 131072, stream>>>(batch_h, W1_h, b1, inner_h, DFF);
  dim3 g2(N_ROWS / 256, DMODEL / 256);  // (64, 4)
  gemm256_tanh<DFF><<<g2, 512, 131072, stream>>>(inner_h, W2_h, b2, wx_h, DMODEL);

  rowdot_sigmoid<<<N_ROWS, 256, 0, stream>>>(wx_h, batch, out);
}

// Round 3
// 425.719 us; speedup vs baseline: 1.6034x; 1.6034x over previous
//
#include <hip/hip_runtime.h>
#include <math.h>

#define N_ROWS 16384
#define DMODEL 1024
#define DFF    4096

typedef _Float16 f16;
typedef __attribute__((ext_vector_type(4))) _Float16 f16x4;
typedef __attribute__((ext_vector_type(8))) _Float16 f16x8;
typedef __attribute__((ext_vector_type(4))) float f32x4;

__device__ inline void async_ld16(const f16* g, f16* l) {
  __builtin_amdgcn_global_load_lds(
      (__attribute__((address_space(1))) void*)(g),
      (__attribute__((address_space(3))) void*)(l),
      16, 0, 0);
}

// tanh via hw v_exp_f32: ~5 VALU ops vs libm tanhf's branchy ~40.
__device__ inline float fast_tanh(float x) {
  float t = __expf(2.0f * x);
  return 1.0f - 2.0f / (t + 1.0f);
}

__global__ void cast_to_f16(const float* __restrict__ src, f16* __restrict__ dst, int n) {
  int i = (blockIdx.x * blockDim.x + threadIdx.x) * 8;
  if (i >= n) return;
  float4 v0 = ((const float4*)(src + i))[0];
  float4 v1 = ((const float4*)(src + i))[1];
  f16x8 h = { (f16)v0.x, (f16)v0.y, (f16)v0.z, (f16)v0.w,
              (f16)v1.x, (f16)v1.y, (f16)v1.z, (f16)v1.w };
  *(f16x8*)(dst + i) = h;
}

#define BARRIER() asm volatile("s_barrier" ::: "memory")

// ---------------------------------------------------------------------------
// C[M,Nc] = tanh(A[M,K] @ B[Nc,K]^T + bias), f16 in/out, fp32 acc.
// 256x256 tile, BK=64, 512 thr (8 waves 2Mx4N, per-wave 128x64 out).
//
// LDS 128KB = 2 dbuf x 4 units x 16KB. Unit = one operand's kk-half:
//   unit0 = A kk0 (256 rows x 32 f16), unit1 = B kk0, unit2 = A kk1, unit3 = B kk1.
// Per K-tile, 4 phases (m201 {8,4,8,4} shape, each phase reads ONLY what its
// 16 MFMAs consume -> frag lifetime = 1 phase, no cross-barrier pressure):
//   P0: read b[kk0 n0-3] + a[kk0 m0-3] (8x b128) | stage unit0(t+1) | bar |
//       setprio1 | 16 MFMA | setprio0 | bar
//   P1: read a[kk0 m4-7] (4)           | stage unit1(t+1) | bar | 16 MFMA |
//       vmcnt(4) | bar      <- units 2,3 of tile t landed (oldest retire first)
//   P2: read b[kk1] + a[kk1 m0-3] (8)  | stage unit2(t+1) | bar | 16 MFMA | bar
//   P3: read a[kk1 m4-7] (4)           | stage unit3(t+1) | bar | 16 MFMA |
//       vmcnt(4) | bar      <- units 0,1 of tile t+1 landed
// Counted vmcnt (T4): per-wave in-flight is always the 4 newest stage instrs;
// in-order vmem retirement + barrier gives cross-wave visibility. Only the
// last tile (no prefetch) drains vmcnt(0) at P1.
// Overwrite safety: unit staged at tile t was last READ >=3 phases earlier
// (kk0 units die after P1 of the previous tile in that dbuf, kk1 after P3).
//
// Swizzle (both-sides, rule #21): unit rows are 64B = 4 x 16B slots; read
// pattern (16 rows x stride 64B) would 8-way conflict. slot ^= row bits 1-2
// -> (row&1, slot) covers all 8 bank-quads uniformly = conflict-free b128.
// Stage side writes LDS linearly (global_load_lds) and pre-permutes the
// GLOBAL source chunk: schunk = (s&3) ^ ((s>>3)&3).
// ---------------------------------------------------------------------------
template <int K>
__global__ __launch_bounds__(512, 2)
void gemm256_tanh(const f16* __restrict__ A, const f16* __restrict__ B,
                  const float* __restrict__ bias, f16* __restrict__ C, int Nc) {
  extern __shared__ __align__(16) char smem[];
  f16* lds = (f16*)smem;

  const int tid  = threadIdx.x;
  const int lane = tid & 63;
  const int wave = tid >> 6;
  const int wm = (wave >> 2) * 128;
  const int wn = (wave & 3) * 64;
  const int fr = lane & 15;
  const int g  = lane >> 4;

  // T1: XCD-aware swizzle (nwg % 8 == 0 for both GEMMs here)
  const int nbx = gridDim.x;
  const int nwg = nbx * gridDim.y;
  const int lin = blockIdx.y * nbx + blockIdx.x;
  const int swz = (lin & 7) * (nwg >> 3) + (lin >> 3);
  const size_t row0 = (size_t)(swz % nbx) * 256;
  const size_t col0 = (size_t)(swz / nbx) * 256;

  // Staging geometry: per unit, thread covers 16B slots s = l*512+tid, l=0,1.
  // srow = s>>2, source chunk pre-swizzled: schunk = (s&3) ^ ((s>>3)&3).
  const int schunk = (tid & 3) ^ ((tid >> 3) & 3);
  const f16* Asrc[2]; const f16* Bsrc[2];
  const int sdst0 = tid * 8;
  const int sdst1 = 4096 + tid * 8;
  Asrc[0] = A + (row0 + (tid >> 2)) * (size_t)K + schunk * 8;
  Asrc[1] = A + (row0 + 128 + (tid >> 2)) * (size_t)K + schunk * 8;
  Bsrc[0] = B + (col0 + (tid >> 2)) * (size_t)K + schunk * 8;
  Bsrc[1] = B + (col0 + 128 + (tid >> 2)) * (size_t)K + schunk * 8;

  // LDS f16-offset helpers (d, kk compile-time foldable where constant)
  auto aoff = [&](int d, int kk, int m) -> int {
    const int row = wm + m * 16 + fr;
    return d * 32768 + kk * 8192 + row * 32 + (g ^ ((row >> 1) & 3)) * 8;
  };
  auto boff = [&](int d, int kk, int n) -> int {
    const int row = wn + n * 16 + fr;
    return d * 32768 + 16384 + kk * 8192 + row * 32 + (g ^ ((row >> 1) & 3)) * 8;
  };
  // stage unit j (0=Akk0,1=Bkk0,2=Akk1,3=Bkk1) of k-base kb into dbuf db
  auto stage_unit = [&](int j, int db, int kb) {
    const int o = j & 1, kk = j >> 1;
    const int dbase = db * 32768 + o * 16384 + kk * 8192;
    async_ld16((o ? Bsrc[0] : Asrc[0]) + kb + kk * 32, lds + dbase + sdst0);
    async_ld16((o ? Bsrc[1] : Asrc[1]) + kb + kk * 32, lds + dbase + sdst1);
  };

  f32x4 acc[8][4] = {};
  constexpr int NT = K / 64;

  // Prologue: stage tile 0 (units 0..3) into dbuf 0; wait units 0,1.
  stage_unit(0, 0, 0);
  stage_unit(1, 0, 0);
  stage_unit(2, 0, 0);
  stage_unit(3, 0, 0);
  asm volatile("s_waitcnt vmcnt(4)" ::: "memory");
  BARRIER();

  for (int t = 0; t < NT; ++t) {
    const int d = t & 1;
    const bool pre = (t + 1) < NT;
    const int kpre = (t + 1) * 64;
    f16x8 bfr[4];

    // ---- P0: kk0, m0-3 ----
    {
      f16x8 afr[4];
#pragma unroll
      for (int n = 0; n < 4; ++n) bfr[n] = *(const f16x8*)(lds + boff(d, 0, n));
#pragma unroll
      for (int i = 0; i < 4; ++i) afr[i] = *(const f16x8*)(lds + aoff(d, 0, i));
      if (pre) stage_unit(0, d ^ 1, kpre);
      BARRIER();
      __builtin_amdgcn_s_setprio(1);
#pragma unroll
      for (int i = 0; i < 4; ++i)
#pragma unroll
        for (int n = 0; n < 4; ++n)
          acc[i][n] = __builtin_amdgcn_mfma_f32_16x16x32_f16(afr[i], bfr[n], acc[i][n], 0, 0, 0);
      __builtin_amdgcn_s_setprio(0);
      BARRIER();
    }
    // ---- P1: kk0, m4-7 ----
    {
      f16x8 afr[4];
#pragma unroll
      for (int i = 0; i < 4; ++i) afr[i] = *(const f16x8*)(lds + aoff(d, 0, 4 + i));
      if (pre) stage_unit(1, d ^ 1, kpre);
      BARRIER();
      __builtin_amdgcn_s_setprio(1);
#pragma unroll
      for (int i = 0; i < 4; ++i)
#pragma unroll
        for (int n = 0; n < 4; ++n)
          acc[4 + i][n] = __builtin_amdgcn_mfma_f32_16x16x32_f16(afr[i], bfr[n], acc[4 + i][n], 0, 0, 0);
      __builtin_amdgcn_s_setprio(0);
      if (pre) asm volatile("s_waitcnt vmcnt(4)" ::: "memory");
      else     asm volatile("s_waitcnt vmcnt(0)" ::: "memory");  // tail drain
      BARRIER();  // units 2,3 of tile t visible to all waves
    }
    // ---- P2: kk1, m0-3 ----
    {
      f16x8 afr[4];
#pragma unroll
      for (int n = 0; n < 4; ++n) bfr[n] = *(const f16x8*)(lds + boff(d, 1, n));
#pragma unroll
      for (int i = 0; i < 4; ++i) afr[i] = *(const f16x8*)(lds + aoff(d, 1, i));
      if (pre) stage_unit(2, d ^ 1, kpre);
      BARRIER();
      __builtin_amdgcn_s_setprio(1);
#pragma unroll
      for (int i = 0; i < 4; ++i)
#pragma unroll
        for (int n = 0; n < 4; ++n)
          acc[i][n] = __builtin_amdgcn_mfma_f32_16x16x32_f16(afr[i], bfr[n], acc[i][n], 0, 0, 0);
      __builtin_amdgcn_s_setprio(0);
      BARRIER();
    }
    // ---- P3: kk1, m4-7 ----
    {
      f16x8 afr[4];
#pragma unroll
      for (int i = 0; i < 4; ++i) afr[i] = *(const f16x8*)(lds + aoff(d, 1, 4 + i));
      if (pre) stage_unit(3, d ^ 1, kpre);
      BARRIER();
      __builtin_amdgcn_s_setprio(1);
#pragma unroll
      for (int i = 0; i < 4; ++i)
#pragma unroll
        for (int n = 0; n < 4; ++n)
          acc[4 + i][n] = __builtin_amdgcn_mfma_f32_16x16x32_f16(afr[i], bfr[n], acc[4 + i][n], 0, 0, 0);
      __builtin_amdgcn_s_setprio(0);
      if (pre) asm volatile("s_waitcnt vmcnt(4)" ::: "memory");  // units 0,1 of t+1
      BARRIER();
    }
  }

  // Epilogue; C/D map: col=lane&15, row=(lane>>4)*4+reg [m89-verified]
#pragma unroll
  for (int m = 0; m < 8; ++m) {
#pragma unroll
    for (int n = 0; n < 4; ++n) {
      const size_t gcol = col0 + wn + n * 16 + fr;
      const float bia = bias[gcol];
      f16* Cp = C + (row0 + wm + m * 16 + g * 4) * (size_t)Nc + gcol;
#pragma unroll
      for (int r = 0; r < 4; ++r)
        Cp[(size_t)r * Nc] = (f16)fast_tanh(acc[m][n][r] + bia);
    }
  }
}

// out[row] = sigmoid(sum_k wx[row][k] * batch[row][k]); 256 thr/row, fp32 acc
__global__ void rowdot_sigmoid(const f16* __restrict__ wx, const float* __restrict__ batch,
                               float* __restrict__ out) {
  const int row = blockIdx.x;
  const int t = threadIdx.x;
  const f16* wr = wx + (size_t)row * DMODEL + t * 4;
  const float* br = batch + (size_t)row * DMODEL + t * 4;
  f16x4 h = *(const f16x4*)wr;
  float4 b4 = *(const float4*)br;
  float s = (float)h[0] * b4.x + (float)h[1] * b4.y + (float)h[2] * b4.z + (float)h[3] * b4.w;
#pragma unroll
  for (int off = 32; off > 0; off >>= 1) s += __shfl_down(s, off, 64);
  __shared__ float partial[4];
  if ((t & 63) == 0) partial[t >> 6] = s;
  __syncthreads();
  if (t == 0) {
    float tot = partial[0] + partial[1] + partial[2] + partial[3];
    out[row] = 1.0f / (1.0f + __expf(-tot));
  }
}

extern "C" void kernel_launch(void* const* d_in, const int* in_sizes, int n_in,
                              void* d_out, int out_size, void* d_ws, size_t ws_size,
                              hipStream_t stream) {
  const float* batch = (const float*)d_in[0];
  const float* W1    = (const float*)d_in[1];
  const float* b1    = (const float*)d_in[2];
  const float* W2    = (const float*)d_in[3];
  const float* b2    = (const float*)d_in[4];
  float* out = (float*)d_out;

  char* ws = (char*)d_ws;
  f16* batch_h = (f16*)ws;  ws += (size_t)N_ROWS * DMODEL * sizeof(f16);  //  32 MB
  f16* W1_h    = (f16*)ws;  ws += (size_t)DFF * DMODEL * sizeof(f16);     //   8 MB
  f16* W2_h    = (f16*)ws;  ws += (size_t)DMODEL * DFF * sizeof(f16);     //   8 MB
  f16* inner_h = (f16*)ws;  ws += (size_t)N_ROWS * DFF * sizeof(f16);     // 128 MB
  f16* wx_h    = (f16*)ws;  ws += (size_t)N_ROWS * DMODEL * sizeof(f16);  //  32 MB

  static bool attr_set = false;
  if (!attr_set) {
    (void)hipFuncSetAttribute((const void*)gemm256_tanh<DMODEL>,
                              hipFuncAttributeMaxDynamicSharedMemorySize, 131072);
    (void)hipFuncSetAttribute((const void*)gemm256_tanh<DFF>,
                              hipFuncAttributeMaxDynamicSharedMemorySize, 131072);
    attr_set = true;
  }

  const int nb = N_ROWS * DMODEL;
  const int nw = DFF * DMODEL;
  cast_to_f16<<<nb / 2048, 256, 0, stream>>>(batch, batch_h, nb);
  cast_to_f16<<<nw / 2048, 256, 0, stream>>>(W1, W1_h, nw);
  cast_to_f16<<<nw / 2048, 256, 0, stream>>>(W2, W2_h, nw);

  dim3 g1(N_ROWS / 256, DFF / 256);     // (64, 16)
  gemm256_tanh<DMODEL><<<g1, 512, 131072, stream>>>(batch_h, W1_h, b1, inner_h, DFF);
  dim3 g2(N_ROWS / 256, DMODEL / 256);  // (64, 4)
  gemm256_tanh<DFF><<<g2, 512, 131072, stream>>>(inner_h, W2_h, b2, wx_h, DMODEL);

  rowdot_sigmoid<<<N_ROWS, 256, 0, stream>>>(wx_h, batch, out);
}